// Round 13
// baseline (1047.232 us; speedup 1.0000x reference)
//
#include <hip/hip_runtime.h>
#include <hip/hip_fp16.h>
#include <cstdint>
#include <cstddef>

// OwnVanillaRNN R13: R12 (compiler-native AGPR, 879 us) + xproj hoisted out
// of the sequential loop.
//   prep_xp: XP[b][t][c] = x@Wx^T + bx as f16 (128 MiB in d_ws, ~27 us GEMM).
//   rnn_main64: 64 h-only frags/thread (53 reg -> V+AGPR via a127-unlock,
//   11 LDS; was 72/19) -> DS -64 KB/step, VALU -40 instr/step. XP streamed
//   1 KB/step/block (L3-resident), prefetched one step ahead.
// Fallback: if ws_size can't hold XP, run the proven R12 path verbatim.

constexpr int BATCH = 256;
constexpr int SEQ   = 512;
constexpr int IN    = 64;
constexpr int HID   = 512;
constexpr int OUT   = 64;
constexpr int T     = 512;

typedef _Float16 half2v __attribute__((ext_vector_type(2)));

__device__ __forceinline__ float fdot2(uint32_t w, uint32_t h, float acc) {
    return __builtin_amdgcn_fdot2(__builtin_bit_cast(half2v, w),
                                  __builtin_bit_cast(half2v, h), acc, false);
}
__device__ __forceinline__ uint32_t packh2(float lo, float hi) {
    return (uint32_t)__half_as_ushort(__float2half(lo)) |
           ((uint32_t)__half_as_ushort(__float2half(hi)) << 16);
}
template <int CTRL>
__device__ __forceinline__ float dpp_add(float v) {
    int i = __builtin_bit_cast(int, v);
    int p = __builtin_amdgcn_update_dpp(i, i, CTRL, 0xF, 0xF, false);
    return v + __builtin_bit_cast(float, p);
}

// ============================= XP path ====================================

// Pack Wh-only frags. Frag k (0..63): p=k>>3 (dim pos), r=k&7 (row in octet).
// Thread t: g=t>>3, s=t&7. Weight = Wh[8g+r][64s+8p .. +7] f16.
__global__ __launch_bounds__(256, 1)
void prep_w64(const float* __restrict__ Wh, uint4* __restrict__ Wpk) {
    const int idx = blockIdx.x * 256 + threadIdx.x;   // 64*512
    const int k = idx >> 9, t = idx & (T - 1);
    const int p = k >> 3, r = k & 7;
    const int g = t >> 3, s = t & 7;
    const float* src = Wh + (size_t)(8 * g + r) * HID + (64 * s + 8 * p);
    uint4 d;
    d.x = packh2(src[0], src[1]);
    d.y = packh2(src[2], src[3]);
    d.z = packh2(src[4], src[5]);
    d.w = packh2(src[6], src[7]);
    Wpk[idx] = d;
}

// XP[b][t][c] = x[b][t][:] @ Wx[c][:] + bx[c], stored f16.
// Block handles 16 (b,t)-rows x 512 cols; thread owns cols {2tid, 2tid+1}.
__global__ __launch_bounds__(256, 1)
void prep_xp(const float* __restrict__ x, const float* __restrict__ Wx,
             const float* __restrict__ bx, __half* __restrict__ XPh) {
    __shared__ uint32_t xs2[16][32];   // 16 rows x 64 f16
    const int tid = threadIdx.x;
    const size_t R0 = (size_t)blockIdx.x * 16;

    for (int e = tid; e < 16 * 32; e += 256) {
        const int r = e >> 5, j = e & 31;
        const float2 v = *(const float2*)(x + (R0 + r) * IN + 2 * j);
        xs2[r][j] = packh2(v.x, v.y);
    }
    const int c0 = 2 * tid, c1 = c0 + 1;
    uint32_t wa[32], wb[32];
    #pragma unroll
    for (int q = 0; q < 16; ++q) {
        const float4 va = *(const float4*)(Wx + (size_t)c0 * IN + 4 * q);
        wa[2 * q] = packh2(va.x, va.y); wa[2 * q + 1] = packh2(va.z, va.w);
        const float4 vb = *(const float4*)(Wx + (size_t)c1 * IN + 4 * q);
        wb[2 * q] = packh2(vb.x, vb.y); wb[2 * q + 1] = packh2(vb.z, vb.w);
    }
    const float b0 = bx[c0], b1 = bx[c1];
    __syncthreads();

    for (int r = 0; r < 16; ++r) {
        float a0 = b0, a1 = b1;
        #pragma unroll
        for (int j = 0; j < 32; ++j) {
            const uint32_t hx = xs2[r][j];
            a0 = fdot2(wa[j], hx, a0);
            a1 = fdot2(wb[j], hx, a1);
        }
        ((uint32_t*)XPh)[((R0 + r) * HID + c0) >> 1] = packh2(a0, a1);
    }
}

#define MV(f, Z) { \
    Z = fdot2(w##f.x, hv.x, Z); Z = fdot2(w##f.y, hv.y, Z); \
    Z = fdot2(w##f.z, hv.z, Z); Z = fdot2(w##f.w, hv.w, Z); }
#define ML(i, Z) { const uint4 wv = wl[(i) * T + t]; \
    Z = fdot2(wv.x, hv.x, Z); Z = fdot2(wv.y, hv.y, Z); \
    Z = fdot2(wv.z, hv.z, Z); Z = fdot2(wv.w, hv.w, Z); }

__global__ __launch_bounds__(T, 2)
__attribute__((amdgpu_waves_per_eu(2, 2)))
void rnn_main64(const float* __restrict__ bh, const float* __restrict__ Wy,
                const float* __restrict__ by, const uint4* __restrict__ Wpk,
                const __half* __restrict__ XPh, float* __restrict__ y) {
    __shared__ uint4 wl[11 * T];                     // 88 KB weights
    __shared__ __align__(16) __half hb2[2][HID];     // double-buffered h

    const int b = blockIdx.x, t = threadIdx.x;
    const int s = t & 7;

    // AGPR unlock (R12-proven): keep the AGPR class live so the allocator
    // spills weight overflow to AGPRs, not scratch.
    {
        uint32_t agk;
        asm volatile("v_accvgpr_write_b32 a127, 0\n\t"
                     "s_nop 1\n\t"
                     "v_accvgpr_read_b32 %0, a127" : "=v"(agk));
        if (agk == 0xDEADBEEFu) hb2[0][0] = __float2half(0.0f);  // never
    }

    #pragma unroll
    for (int i = 0; i < 11; ++i)
        wl[i * T + t] = Wpk[(size_t)(53 + i) * T + t];

#define DECL_WV(f) const uint4 w##f = Wpk[(size_t)(f) * T + t];
    DECL_WV(0)  DECL_WV(1)  DECL_WV(2)  DECL_WV(3)  DECL_WV(4)  DECL_WV(5)
    DECL_WV(6)  DECL_WV(7)  DECL_WV(8)  DECL_WV(9)  DECL_WV(10) DECL_WV(11)
    DECL_WV(12) DECL_WV(13) DECL_WV(14) DECL_WV(15) DECL_WV(16) DECL_WV(17)
    DECL_WV(18) DECL_WV(19) DECL_WV(20) DECL_WV(21) DECL_WV(22) DECL_WV(23)
    DECL_WV(24) DECL_WV(25) DECL_WV(26) DECL_WV(27) DECL_WV(28) DECL_WV(29)
    DECL_WV(30) DECL_WV(31) DECL_WV(32) DECL_WV(33) DECL_WV(34) DECL_WV(35)
    DECL_WV(36) DECL_WV(37) DECL_WV(38) DECL_WV(39) DECL_WV(40) DECL_WV(41)
    DECL_WV(42) DECL_WV(43) DECL_WV(44) DECL_WV(45) DECL_WV(46) DECL_WV(47)
    DECL_WV(48) DECL_WV(49) DECL_WV(50) DECL_WV(51) DECL_WV(52)
#undef DECL_WV

    const float bs = bh[t];
    const __half* XProw = XPh + ((size_t)b * SEQ) * HID + t;

    hb2[0][t] = __float2half(0.0f);   // h0 = 0
    float xpc = __half2float(XProw[0]);
    __syncthreads();

    #pragma unroll 1
    for (int tt = 0; tt < SEQ; ++tt) {
        const int c = tt & 1;
        // prefetch next step's xproj (L3-resident; full step to cover)
        float xpn = 0.0f;
        if (tt + 1 < SEQ) xpn = __half2float(XProw[(size_t)(tt + 1) * HID]);

        const uint4* hb = (const uint4*)(&hb2[c][0] + 64 * s);
        float z0 = 0.f, z1 = 0.f, z2 = 0.f, z3 = 0.f;
        float z4 = 0.f, z5 = 0.f, z6 = 0.f, z7 = 0.f;

        { const uint4 hv = hb[0];
          MV(0,z0) MV(1,z1) MV(2,z2) MV(3,z3) MV(4,z4) MV(5,z5) MV(6,z6) MV(7,z7) }
        { const uint4 hv = hb[1];
          MV(8,z0) MV(9,z1) MV(10,z2) MV(11,z3) MV(12,z4) MV(13,z5) MV(14,z6) MV(15,z7) }
        { const uint4 hv = hb[2];
          MV(16,z0) MV(17,z1) MV(18,z2) MV(19,z3) MV(20,z4) MV(21,z5) MV(22,z6) MV(23,z7) }
        { const uint4 hv = hb[3];
          MV(24,z0) MV(25,z1) MV(26,z2) MV(27,z3) MV(28,z4) MV(29,z5) MV(30,z6) MV(31,z7) }
        { const uint4 hv = hb[4];
          MV(32,z0) MV(33,z1) MV(34,z2) MV(35,z3) MV(36,z4) MV(37,z5) MV(38,z6) MV(39,z7) }
        { const uint4 hv = hb[5];
          MV(40,z0) MV(41,z1) MV(42,z2) MV(43,z3) MV(44,z4) MV(45,z5) MV(46,z6) MV(47,z7) }
        { const uint4 hv = hb[6];
          MV(48,z0) MV(49,z1) MV(50,z2) MV(51,z3) MV(52,z4) ML(0,z5) ML(1,z6) ML(2,z7) }
        { const uint4 hv = hb[7];
          ML(3,z0) ML(4,z1) ML(5,z2) ML(6,z3) ML(7,z4) ML(8,z5) ML(9,z6) ML(10,z7) }

        // 8-way K-reduce (R11-verified): every lane ends with full sums.
        z0 = dpp_add<0xB1>(z0); z0 = dpp_add<0x4E>(z0); z0 = dpp_add<0x141>(z0);
        z1 = dpp_add<0xB1>(z1); z1 = dpp_add<0x4E>(z1); z1 = dpp_add<0x141>(z1);
        z2 = dpp_add<0xB1>(z2); z2 = dpp_add<0x4E>(z2); z2 = dpp_add<0x141>(z2);
        z3 = dpp_add<0xB1>(z3); z3 = dpp_add<0x4E>(z3); z3 = dpp_add<0x141>(z3);
        z4 = dpp_add<0xB1>(z4); z4 = dpp_add<0x4E>(z4); z4 = dpp_add<0x141>(z4);
        z5 = dpp_add<0xB1>(z5); z5 = dpp_add<0x4E>(z5); z5 = dpp_add<0x141>(z5);
        z6 = dpp_add<0xB1>(z6); z6 = dpp_add<0x4E>(z6); z6 = dpp_add<0x141>(z6);
        z7 = dpp_add<0xB1>(z7); z7 = dpp_add<0x4E>(z7); z7 = dpp_add<0x141>(z7);

        // All-lane epilogue: lane s selects z_s; one tanh; contiguous write.
        const float za = (s & 1) ? z1 : z0;
        const float zb = (s & 1) ? z3 : z2;
        const float zc = (s & 1) ? z5 : z4;
        const float zd = (s & 1) ? z7 : z6;
        const float ze = (s & 2) ? zb : za;
        const float zf = (s & 2) ? zd : zc;
        const float zz = (s & 4) ? zf : ze;
        const float hh = 1.f - 2.f * __builtin_amdgcn_rcpf(
                             __expf(2.f * (zz + bs + xpc)) + 1.f);
        hb2[c ^ 1][t] = __float2half(hh);
        xpc = xpn;
        __syncthreads();
    }

    if (t < OUT) {
        float acc = by[t];
        const float* wy = Wy + (size_t)t * HID;
        #pragma unroll 8
        for (int j = 0; j < HID; ++j)
            acc = fmaf(wy[j], __half2float(hb2[0][j]), acc);
        y[(size_t)b * OUT + t] = acc;
    }
}

// ====================== Fallback path (R12 verbatim) ======================

constexpr int DTOT  = HID + IN;
constexpr int DSL72 = DTOT / 8;
constexpr int NL72  = 19;
constexpr int KL072 = 53;

__global__ __launch_bounds__(256, 1)
void prep_w72(const float* __restrict__ Wh, const float* __restrict__ Wx,
              uint4* __restrict__ Wpk) {
    const int idx = blockIdx.x * 256 + threadIdx.x;
    const int k = idx >> 9, t = idx & (T - 1);
    const int p = k >> 3, r = k & 7;
    const int g = t >> 3, s = t & 7;
    const int o = 8 * g + r;
    const int d0 = DSL72 * s + 8 * p;
    const float* src = (d0 < HID) ? (Wh + (size_t)o * HID + d0)
                                  : (Wx + (size_t)o * IN + (d0 - HID));
    uint4 d;
    d.x = packh2(src[0], src[1]);
    d.y = packh2(src[2], src[3]);
    d.z = packh2(src[4], src[5]);
    d.w = packh2(src[6], src[7]);
    Wpk[idx] = d;
}

#define ML72(i, Z) { const uint4 wv = wl[t * NL72 + (i)]; \
    Z = fdot2(wv.x, hv.x, Z); Z = fdot2(wv.y, hv.y, Z); \
    Z = fdot2(wv.z, hv.z, Z); Z = fdot2(wv.w, hv.w, Z); }

__global__ __launch_bounds__(T, 2)
__attribute__((amdgpu_waves_per_eu(2, 2)))
void rnn_main72(const float* __restrict__ x,  const float* __restrict__ bx,
                const float* __restrict__ bh, const float* __restrict__ Wy,
                const float* __restrict__ by, const uint4* __restrict__ Wpk,
                float* __restrict__ y) {
    __shared__ uint4 wl[T * NL72];
    __shared__ __align__(16) __half hb2[2][DTOT];

    const int b = blockIdx.x, t = threadIdx.x;
    const int s = t & 7;
    {
        uint32_t agk;
        asm volatile("v_accvgpr_write_b32 a127, 0\n\t"
                     "s_nop 1\n\t"
                     "v_accvgpr_read_b32 %0, a127" : "=v"(agk));
        if (agk == 0xDEADBEEFu) hb2[0][0] = __float2half(0.0f);
    }
    #pragma unroll
    for (int i = 0; i < NL72; ++i)
        wl[t * NL72 + i] = Wpk[(size_t)(KL072 + i) * T + t];

#define DECL_WV(f) const uint4 w##f = Wpk[(size_t)(f) * T + t];
    DECL_WV(0)  DECL_WV(1)  DECL_WV(2)  DECL_WV(3)  DECL_WV(4)  DECL_WV(5)
    DECL_WV(6)  DECL_WV(7)  DECL_WV(8)  DECL_WV(9)  DECL_WV(10) DECL_WV(11)
    DECL_WV(12) DECL_WV(13) DECL_WV(14) DECL_WV(15) DECL_WV(16) DECL_WV(17)
    DECL_WV(18) DECL_WV(19) DECL_WV(20) DECL_WV(21) DECL_WV(22) DECL_WV(23)
    DECL_WV(24) DECL_WV(25) DECL_WV(26) DECL_WV(27) DECL_WV(28) DECL_WV(29)
    DECL_WV(30) DECL_WV(31) DECL_WV(32) DECL_WV(33) DECL_WV(34) DECL_WV(35)
    DECL_WV(36) DECL_WV(37) DECL_WV(38) DECL_WV(39) DECL_WV(40) DECL_WV(41)
    DECL_WV(42) DECL_WV(43) DECL_WV(44) DECL_WV(45) DECL_WV(46) DECL_WV(47)
    DECL_WV(48) DECL_WV(49) DECL_WV(50) DECL_WV(51) DECL_WV(52)
#undef DECL_WV

    const float bs = bx[t] + bh[t];
    const float* xb = x + (size_t)b * SEQ * IN;

    hb2[0][t] = __float2half(0.0f);
    if (t < IN) hb2[0][HID + t] = __float2half(xb[t]);
    float xv = (t < IN) ? xb[IN + t] : 0.0f;
    __syncthreads();

    #pragma unroll 1
    for (int tt = 0; tt < SEQ; ++tt) {
        const int c = tt & 1;
        const uint4* hb = (const uint4*)(&hb2[c][0] + DSL72 * s);
        float z0 = 0.f, z1 = 0.f, z2 = 0.f, z3 = 0.f;
        float z4 = 0.f, z5 = 0.f, z6 = 0.f, z7 = 0.f;

        { const uint4 hv = hb[0];
          MV(0,z0) MV(1,z1) MV(2,z2) MV(3,z3) MV(4,z4) MV(5,z5) MV(6,z6) MV(7,z7) }
        { const uint4 hv = hb[1];
          MV(8,z0) MV(9,z1) MV(10,z2) MV(11,z3) MV(12,z4) MV(13,z5) MV(14,z6) MV(15,z7) }
        { const uint4 hv = hb[2];
          MV(16,z0) MV(17,z1) MV(18,z2) MV(19,z3) MV(20,z4) MV(21,z5) MV(22,z6) MV(23,z7) }
        { const uint4 hv = hb[3];
          MV(24,z0) MV(25,z1) MV(26,z2) MV(27,z3) MV(28,z4) MV(29,z5) MV(30,z6) MV(31,z7) }
        { const uint4 hv = hb[4];
          MV(32,z0) MV(33,z1) MV(34,z2) MV(35,z3) MV(36,z4) MV(37,z5) MV(38,z6) MV(39,z7) }
        { const uint4 hv = hb[5];
          MV(40,z0) MV(41,z1) MV(42,z2) MV(43,z3) MV(44,z4) MV(45,z5) MV(46,z6) MV(47,z7) }
        { const uint4 hv = hb[6];
          MV(48,z0) MV(49,z1) MV(50,z2) MV(51,z3) MV(52,z4) ML72(0,z5) ML72(1,z6) ML72(2,z7) }
        { const uint4 hv = hb[7];
          ML72(3,z0) ML72(4,z1) ML72(5,z2) ML72(6,z3) ML72(7,z4) ML72(8,z5) ML72(9,z6) ML72(10,z7) }
        { const uint4 hv = hb[8];
          ML72(11,z0) ML72(12,z1) ML72(13,z2) ML72(14,z3) ML72(15,z4) ML72(16,z5) ML72(17,z6) ML72(18,z7) }

        z0 = dpp_add<0xB1>(z0); z0 = dpp_add<0x4E>(z0); z0 = dpp_add<0x141>(z0);
        z1 = dpp_add<0xB1>(z1); z1 = dpp_add<0x4E>(z1); z1 = dpp_add<0x141>(z1);
        z2 = dpp_add<0xB1>(z2); z2 = dpp_add<0x4E>(z2); z2 = dpp_add<0x141>(z2);
        z3 = dpp_add<0xB1>(z3); z3 = dpp_add<0x4E>(z3); z3 = dpp_add<0x141>(z3);
        z4 = dpp_add<0xB1>(z4); z4 = dpp_add<0x4E>(z4); z4 = dpp_add<0x141>(z4);
        z5 = dpp_add<0xB1>(z5); z5 = dpp_add<0x4E>(z5); z5 = dpp_add<0x141>(z5);
        z6 = dpp_add<0xB1>(z6); z6 = dpp_add<0x4E>(z6); z6 = dpp_add<0x141>(z6);
        z7 = dpp_add<0xB1>(z7); z7 = dpp_add<0x4E>(z7); z7 = dpp_add<0x141>(z7);

        const float za = (s & 1) ? z1 : z0;
        const float zb = (s & 1) ? z3 : z2;
        const float zc = (s & 1) ? z5 : z4;
        const float zd = (s & 1) ? z7 : z6;
        const float ze = (s & 2) ? zb : za;
        const float zf = (s & 2) ? zd : zc;
        const float zz = (s & 4) ? zf : ze;
        const float hh = 1.f - 2.f * __builtin_amdgcn_rcpf(__expf(2.f * (zz + bs)) + 1.f);
        hb2[c ^ 1][t] = __float2half(hh);

        if (t < IN) {
            hb2[c ^ 1][HID + t] = __float2half(xv);
            if (tt + 2 < SEQ) xv = xb[(size_t)(tt + 2) * IN + t];
        }
        __syncthreads();
    }

    if (t < OUT) {
        float acc = by[t];
        const float* wy = Wy + (size_t)t * HID;
        #pragma unroll 8
        for (int j = 0; j < HID; ++j)
            acc = fmaf(wy[j], __half2float(hb2[0][j]), acc);
        y[(size_t)b * OUT + t] = acc;
    }
}

extern "C" void kernel_launch(void* const* d_in, const int* in_sizes, int n_in,
                              void* d_out, int out_size, void* d_ws, size_t ws_size,
                              hipStream_t stream) {
    const float* x  = (const float*)d_in[0];
    const float* Wx = (const float*)d_in[1];
    const float* bx = (const float*)d_in[2];
    const float* Wh = (const float*)d_in[3];
    const float* bh = (const float*)d_in[4];
    const float* Wy = (const float*)d_in[5];
    const float* by = (const float*)d_in[6];
    float* y = (float*)d_out;

    const size_t wpk_bytes = (size_t)72 * T * 16;               // 576 KB max
    const size_t xp_bytes  = (size_t)BATCH * SEQ * HID * 2;     // 128 MiB
    if (ws_size >= wpk_bytes + xp_bytes) {
        uint4*  Wpk = (uint4*)d_ws;
        __half* XPh = (__half*)((char*)d_ws + wpk_bytes);
        hipLaunchKernelGGL(prep_w64, dim3(64 * T / 256), dim3(256), 0, stream,
                           Wh, Wpk);
        hipLaunchKernelGGL(prep_xp, dim3(BATCH * SEQ / 16), dim3(256), 0, stream,
                           x, Wx, bx, XPh);
        hipLaunchKernelGGL(rnn_main64, dim3(BATCH), dim3(T), 0, stream,
                           bh, Wy, by, Wpk, XPh, y);
    } else {
        uint4* Wpk = (uint4*)d_ws;
        hipLaunchKernelGGL(prep_w72, dim3(72 * T / 256), dim3(256), 0, stream,
                           Wh, Wx, Wpk);
        hipLaunchKernelGGL(rnn_main72, dim3(BATCH), dim3(T), 0, stream,
                           x, bx, bh, Wy, by, Wpk, y);
    }
}

// Round 14
// 1045.384 us; speedup vs baseline: 1.0018x; 1.0018x over previous
//
#include <hip/hip_runtime.h>
#include <hip/hip_fp16.h>
#include <cstdint>
#include <cstddef>

// OwnVanillaRNN R14: R13 (xproj hoisted, 64 h-frags) + bank-conflict fix.
// R13 bug: h-slice stride became 64 halves = 128 B -> all 8 slices' broadcast
// reads hit bank quad 4j (1.0e8 conflicts, +0.32 us/step). Fix: pad each
// slice to 72 halves (144 B, = R12's accidental geometry): bank (4s+4j)%32,
// all distinct. Everything else from R13 unchanged (compiler-native AGPR via
// a127 unlock, XP f16 stream prefetched 1 step ahead, all-lane epilogue).

constexpr int BATCH = 256;
constexpr int SEQ   = 512;
constexpr int IN    = 64;
constexpr int HID   = 512;
constexpr int OUT   = 64;
constexpr int T     = 512;
constexpr int PADSL = 72;     // halves per 64-dim slice incl. 8-half pad

typedef _Float16 half2v __attribute__((ext_vector_type(2)));

__device__ __forceinline__ float fdot2(uint32_t w, uint32_t h, float acc) {
    return __builtin_amdgcn_fdot2(__builtin_bit_cast(half2v, w),
                                  __builtin_bit_cast(half2v, h), acc, false);
}
__device__ __forceinline__ uint32_t packh2(float lo, float hi) {
    return (uint32_t)__half_as_ushort(__float2half(lo)) |
           ((uint32_t)__half_as_ushort(__float2half(hi)) << 16);
}
template <int CTRL>
__device__ __forceinline__ float dpp_add(float v) {
    int i = __builtin_bit_cast(int, v);
    int p = __builtin_amdgcn_update_dpp(i, i, CTRL, 0xF, 0xF, false);
    return v + __builtin_bit_cast(float, p);
}
__device__ __forceinline__ int padidx(int d) {     // h row d -> padded half idx
    return PADSL * (d >> 6) + (d & 63);
}

// ============================= XP path ====================================

// Pack Wh-only frags. Frag k (0..63): p=k>>3 (dim pos), r=k&7 (row in octet).
// Thread t: g=t>>3, s=t&7. Weight = Wh[8g+r][64s+8p .. +7] f16.
__global__ __launch_bounds__(256, 1)
void prep_w64(const float* __restrict__ Wh, uint4* __restrict__ Wpk) {
    const int idx = blockIdx.x * 256 + threadIdx.x;   // 64*512
    const int k = idx >> 9, t = idx & (T - 1);
    const int p = k >> 3, r = k & 7;
    const int g = t >> 3, s = t & 7;
    const float* src = Wh + (size_t)(8 * g + r) * HID + (64 * s + 8 * p);
    uint4 d;
    d.x = packh2(src[0], src[1]);
    d.y = packh2(src[2], src[3]);
    d.z = packh2(src[4], src[5]);
    d.w = packh2(src[6], src[7]);
    Wpk[idx] = d;
}

// XP[b][t][c] = x[b][t][:] @ Wx[c][:] + bx[c], stored f16.
__global__ __launch_bounds__(256, 1)
void prep_xp(const float* __restrict__ x, const float* __restrict__ Wx,
             const float* __restrict__ bx, __half* __restrict__ XPh) {
    __shared__ uint32_t xs2[16][32];   // 16 rows x 64 f16
    const int tid = threadIdx.x;
    const size_t R0 = (size_t)blockIdx.x * 16;

    for (int e = tid; e < 16 * 32; e += 256) {
        const int r = e >> 5, j = e & 31;
        const float2 v = *(const float2*)(x + (R0 + r) * IN + 2 * j);
        xs2[r][j] = packh2(v.x, v.y);
    }
    const int c0 = 2 * tid, c1 = c0 + 1;
    uint32_t wa[32], wb[32];
    #pragma unroll
    for (int q = 0; q < 16; ++q) {
        const float4 va = *(const float4*)(Wx + (size_t)c0 * IN + 4 * q);
        wa[2 * q] = packh2(va.x, va.y); wa[2 * q + 1] = packh2(va.z, va.w);
        const float4 vb = *(const float4*)(Wx + (size_t)c1 * IN + 4 * q);
        wb[2 * q] = packh2(vb.x, vb.y); wb[2 * q + 1] = packh2(vb.z, vb.w);
    }
    const float b0 = bx[c0], b1 = bx[c1];
    __syncthreads();

    for (int r = 0; r < 16; ++r) {
        float a0 = b0, a1 = b1;
        #pragma unroll
        for (int j = 0; j < 32; ++j) {
            const uint32_t hx = xs2[r][j];
            a0 = fdot2(wa[j], hx, a0);
            a1 = fdot2(wb[j], hx, a1);
        }
        ((uint32_t*)XPh)[((R0 + r) * HID + c0) >> 1] = packh2(a0, a1);
    }
}

#define MV(f, Z) { \
    Z = fdot2(w##f.x, hv.x, Z); Z = fdot2(w##f.y, hv.y, Z); \
    Z = fdot2(w##f.z, hv.z, Z); Z = fdot2(w##f.w, hv.w, Z); }
#define ML(i, Z) { const uint4 wv = wl[(i) * T + t]; \
    Z = fdot2(wv.x, hv.x, Z); Z = fdot2(wv.y, hv.y, Z); \
    Z = fdot2(wv.z, hv.z, Z); Z = fdot2(wv.w, hv.w, Z); }

__global__ __launch_bounds__(T, 2)
__attribute__((amdgpu_waves_per_eu(2, 2)))
void rnn_main64(const float* __restrict__ bh, const float* __restrict__ Wy,
                const float* __restrict__ by, const uint4* __restrict__ Wpk,
                const __half* __restrict__ XPh, float* __restrict__ y) {
    __shared__ uint4 wl[11 * T];                       // 88 KB weights
    __shared__ __align__(16) __half hb2[2][8 * PADSL]; // padded dbuf h

    const int b = blockIdx.x, t = threadIdx.x;
    const int s = t & 7;

    // AGPR unlock (R12-proven): keep the AGPR class live so the allocator
    // spills weight overflow to AGPRs, not scratch.
    {
        uint32_t agk;
        asm volatile("v_accvgpr_write_b32 a127, 0\n\t"
                     "s_nop 1\n\t"
                     "v_accvgpr_read_b32 %0, a127" : "=v"(agk));
        if (agk == 0xDEADBEEFu) hb2[0][0] = __float2half(0.0f);  // never
    }

    #pragma unroll
    for (int i = 0; i < 11; ++i)
        wl[i * T + t] = Wpk[(size_t)(53 + i) * T + t];

#define DECL_WV(f) const uint4 w##f = Wpk[(size_t)(f) * T + t];
    DECL_WV(0)  DECL_WV(1)  DECL_WV(2)  DECL_WV(3)  DECL_WV(4)  DECL_WV(5)
    DECL_WV(6)  DECL_WV(7)  DECL_WV(8)  DECL_WV(9)  DECL_WV(10) DECL_WV(11)
    DECL_WV(12) DECL_WV(13) DECL_WV(14) DECL_WV(15) DECL_WV(16) DECL_WV(17)
    DECL_WV(18) DECL_WV(19) DECL_WV(20) DECL_WV(21) DECL_WV(22) DECL_WV(23)
    DECL_WV(24) DECL_WV(25) DECL_WV(26) DECL_WV(27) DECL_WV(28) DECL_WV(29)
    DECL_WV(30) DECL_WV(31) DECL_WV(32) DECL_WV(33) DECL_WV(34) DECL_WV(35)
    DECL_WV(36) DECL_WV(37) DECL_WV(38) DECL_WV(39) DECL_WV(40) DECL_WV(41)
    DECL_WV(42) DECL_WV(43) DECL_WV(44) DECL_WV(45) DECL_WV(46) DECL_WV(47)
    DECL_WV(48) DECL_WV(49) DECL_WV(50) DECL_WV(51) DECL_WV(52)
#undef DECL_WV

    const float bs = bh[t];
    const __half* XProw = XPh + ((size_t)b * SEQ) * HID + t;

    hb2[0][padidx(t)] = __float2half(0.0f);   // h0 = 0
    float xpc = __half2float(XProw[0]);
    __syncthreads();

    #pragma unroll 1
    for (int tt = 0; tt < SEQ; ++tt) {
        const int c = tt & 1;
        // prefetch next step's xproj (L3/HBM; full step of compute to cover)
        float xpn = 0.0f;
        if (tt + 1 < SEQ) xpn = __half2float(XProw[(size_t)(tt + 1) * HID]);

        // slice s base = 144*s bytes -> banks (4s+4j)%32, all distinct.
        const uint4* hb = (const uint4*)((const __half*)hb2[c] + PADSL * s);
        float z0 = 0.f, z1 = 0.f, z2 = 0.f, z3 = 0.f;
        float z4 = 0.f, z5 = 0.f, z6 = 0.f, z7 = 0.f;

        { const uint4 hv = hb[0];
          MV(0,z0) MV(1,z1) MV(2,z2) MV(3,z3) MV(4,z4) MV(5,z5) MV(6,z6) MV(7,z7) }
        { const uint4 hv = hb[1];
          MV(8,z0) MV(9,z1) MV(10,z2) MV(11,z3) MV(12,z4) MV(13,z5) MV(14,z6) MV(15,z7) }
        { const uint4 hv = hb[2];
          MV(16,z0) MV(17,z1) MV(18,z2) MV(19,z3) MV(20,z4) MV(21,z5) MV(22,z6) MV(23,z7) }
        { const uint4 hv = hb[3];
          MV(24,z0) MV(25,z1) MV(26,z2) MV(27,z3) MV(28,z4) MV(29,z5) MV(30,z6) MV(31,z7) }
        { const uint4 hv = hb[4];
          MV(32,z0) MV(33,z1) MV(34,z2) MV(35,z3) MV(36,z4) MV(37,z5) MV(38,z6) MV(39,z7) }
        { const uint4 hv = hb[5];
          MV(40,z0) MV(41,z1) MV(42,z2) MV(43,z3) MV(44,z4) MV(45,z5) MV(46,z6) MV(47,z7) }
        { const uint4 hv = hb[6];
          MV(48,z0) MV(49,z1) MV(50,z2) MV(51,z3) MV(52,z4) ML(0,z5) ML(1,z6) ML(2,z7) }
        { const uint4 hv = hb[7];
          ML(3,z0) ML(4,z1) ML(5,z2) ML(6,z3) ML(7,z4) ML(8,z5) ML(9,z6) ML(10,z7) }

        // 8-way K-reduce (R11-verified): every lane ends with full sums.
        z0 = dpp_add<0xB1>(z0); z0 = dpp_add<0x4E>(z0); z0 = dpp_add<0x141>(z0);
        z1 = dpp_add<0xB1>(z1); z1 = dpp_add<0x4E>(z1); z1 = dpp_add<0x141>(z1);
        z2 = dpp_add<0xB1>(z2); z2 = dpp_add<0x4E>(z2); z2 = dpp_add<0x141>(z2);
        z3 = dpp_add<0xB1>(z3); z3 = dpp_add<0x4E>(z3); z3 = dpp_add<0x141>(z3);
        z4 = dpp_add<0xB1>(z4); z4 = dpp_add<0x4E>(z4); z4 = dpp_add<0x141>(z4);
        z5 = dpp_add<0xB1>(z5); z5 = dpp_add<0x4E>(z5); z5 = dpp_add<0x141>(z5);
        z6 = dpp_add<0xB1>(z6); z6 = dpp_add<0x4E>(z6); z6 = dpp_add<0x141>(z6);
        z7 = dpp_add<0xB1>(z7); z7 = dpp_add<0x4E>(z7); z7 = dpp_add<0x141>(z7);

        // All-lane epilogue: lane s selects z_s; one tanh; padded write.
        const float za = (s & 1) ? z1 : z0;
        const float zb = (s & 1) ? z3 : z2;
        const float zc = (s & 1) ? z5 : z4;
        const float zd = (s & 1) ? z7 : z6;
        const float ze = (s & 2) ? zb : za;
        const float zf = (s & 2) ? zd : zc;
        const float zz = (s & 4) ? zf : ze;
        const float hh = 1.f - 2.f * __builtin_amdgcn_rcpf(
                             __expf(2.f * (zz + bs + xpc)) + 1.f);
        hb2[c ^ 1][padidx(t)] = __float2half(hh);
        xpc = xpn;
        __syncthreads();
    }

    if (t < OUT) {
        float acc = by[t];
        const float* wy = Wy + (size_t)t * HID;
        #pragma unroll 8
        for (int j = 0; j < HID; ++j)
            acc = fmaf(wy[j], __half2float(hb2[0][padidx(j)]), acc);
        y[(size_t)b * OUT + t] = acc;
    }
}

// ====================== Fallback path (R12 verbatim) ======================

constexpr int DTOT  = HID + IN;
constexpr int DSL72 = DTOT / 8;
constexpr int NL72  = 19;
constexpr int KL072 = 53;

__global__ __launch_bounds__(256, 1)
void prep_w72(const float* __restrict__ Wh, const float* __restrict__ Wx,
              uint4* __restrict__ Wpk) {
    const int idx = blockIdx.x * 256 + threadIdx.x;
    const int k = idx >> 9, t = idx & (T - 1);
    const int p = k >> 3, r = k & 7;
    const int g = t >> 3, s = t & 7;
    const int o = 8 * g + r;
    const int d0 = DSL72 * s + 8 * p;
    const float* src = (d0 < HID) ? (Wh + (size_t)o * HID + d0)
                                  : (Wx + (size_t)o * IN + (d0 - HID));
    uint4 d;
    d.x = packh2(src[0], src[1]);
    d.y = packh2(src[2], src[3]);
    d.z = packh2(src[4], src[5]);
    d.w = packh2(src[6], src[7]);
    Wpk[idx] = d;
}

#define ML72(i, Z) { const uint4 wv = wl[t * NL72 + (i)]; \
    Z = fdot2(wv.x, hv.x, Z); Z = fdot2(wv.y, hv.y, Z); \
    Z = fdot2(wv.z, hv.z, Z); Z = fdot2(wv.w, hv.w, Z); }

__global__ __launch_bounds__(T, 2)
__attribute__((amdgpu_waves_per_eu(2, 2)))
void rnn_main72(const float* __restrict__ x,  const float* __restrict__ bx,
                const float* __restrict__ bh, const float* __restrict__ Wy,
                const float* __restrict__ by, const uint4* __restrict__ Wpk,
                float* __restrict__ y) {
    __shared__ uint4 wl[T * NL72];
    __shared__ __align__(16) __half hb2[2][DTOT];

    const int b = blockIdx.x, t = threadIdx.x;
    const int s = t & 7;
    {
        uint32_t agk;
        asm volatile("v_accvgpr_write_b32 a127, 0\n\t"
                     "s_nop 1\n\t"
                     "v_accvgpr_read_b32 %0, a127" : "=v"(agk));
        if (agk == 0xDEADBEEFu) hb2[0][0] = __float2half(0.0f);
    }
    #pragma unroll
    for (int i = 0; i < NL72; ++i)
        wl[t * NL72 + i] = Wpk[(size_t)(KL072 + i) * T + t];

#define DECL_WV(f) const uint4 w##f = Wpk[(size_t)(f) * T + t];
    DECL_WV(0)  DECL_WV(1)  DECL_WV(2)  DECL_WV(3)  DECL_WV(4)  DECL_WV(5)
    DECL_WV(6)  DECL_WV(7)  DECL_WV(8)  DECL_WV(9)  DECL_WV(10) DECL_WV(11)
    DECL_WV(12) DECL_WV(13) DECL_WV(14) DECL_WV(15) DECL_WV(16) DECL_WV(17)
    DECL_WV(18) DECL_WV(19) DECL_WV(20) DECL_WV(21) DECL_WV(22) DECL_WV(23)
    DECL_WV(24) DECL_WV(25) DECL_WV(26) DECL_WV(27) DECL_WV(28) DECL_WV(29)
    DECL_WV(30) DECL_WV(31) DECL_WV(32) DECL_WV(33) DECL_WV(34) DECL_WV(35)
    DECL_WV(36) DECL_WV(37) DECL_WV(38) DECL_WV(39) DECL_WV(40) DECL_WV(41)
    DECL_WV(42) DECL_WV(43) DECL_WV(44) DECL_WV(45) DECL_WV(46) DECL_WV(47)
    DECL_WV(48) DECL_WV(49) DECL_WV(50) DECL_WV(51) DECL_WV(52)
#undef DECL_WV

    const float bs = bx[t] + bh[t];
    const float* xb = x + (size_t)b * SEQ * IN;

    hb2[0][t] = __float2half(0.0f);
    if (t < IN) hb2[0][HID + t] = __float2half(xb[t]);
    float xv = (t < IN) ? xb[IN + t] : 0.0f;
    __syncthreads();

    #pragma unroll 1
    for (int tt = 0; tt < SEQ; ++tt) {
        const int c = tt & 1;
        const uint4* hb = (const uint4*)(&hb2[c][0] + DSL72 * s);
        float z0 = 0.f, z1 = 0.f, z2 = 0.f, z3 = 0.f;
        float z4 = 0.f, z5 = 0.f, z6 = 0.f, z7 = 0.f;

        { const uint4 hv = hb[0];
          MV(0,z0) MV(1,z1) MV(2,z2) MV(3,z3) MV(4,z4) MV(5,z5) MV(6,z6) MV(7,z7) }
        { const uint4 hv = hb[1];
          MV(8,z0) MV(9,z1) MV(10,z2) MV(11,z3) MV(12,z4) MV(13,z5) MV(14,z6) MV(15,z7) }
        { const uint4 hv = hb[2];
          MV(16,z0) MV(17,z1) MV(18,z2) MV(19,z3) MV(20,z4) MV(21,z5) MV(22,z6) MV(23,z7) }
        { const uint4 hv = hb[3];
          MV(24,z0) MV(25,z1) MV(26,z2) MV(27,z3) MV(28,z4) MV(29,z5) MV(30,z6) MV(31,z7) }
        { const uint4 hv = hb[4];
          MV(32,z0) MV(33,z1) MV(34,z2) MV(35,z3) MV(36,z4) MV(37,z5) MV(38,z6) MV(39,z7) }
        { const uint4 hv = hb[5];
          MV(40,z0) MV(41,z1) MV(42,z2) MV(43,z3) MV(44,z4) MV(45,z5) MV(46,z6) MV(47,z7) }
        { const uint4 hv = hb[6];
          MV(48,z0) MV(49,z1) MV(50,z2) MV(51,z3) MV(52,z4) ML72(0,z5) ML72(1,z6) ML72(2,z7) }
        { const uint4 hv = hb[7];
          ML72(3,z0) ML72(4,z1) ML72(5,z2) ML72(6,z3) ML72(7,z4) ML72(8,z5) ML72(9,z6) ML72(10,z7) }
        { const uint4 hv = hb[8];
          ML72(11,z0) ML72(12,z1) ML72(13,z2) ML72(14,z3) ML72(15,z4) ML72(16,z5) ML72(17,z6) ML72(18,z7) }

        z0 = dpp_add<0xB1>(z0); z0 = dpp_add<0x4E>(z0); z0 = dpp_add<0x141>(z0);
        z1 = dpp_add<0xB1>(z1); z1 = dpp_add<0x4E>(z1); z1 = dpp_add<0x141>(z1);
        z2 = dpp_add<0xB1>(z2); z2 = dpp_add<0x4E>(z2); z2 = dpp_add<0x141>(z2);
        z3 = dpp_add<0xB1>(z3); z3 = dpp_add<0x4E>(z3); z3 = dpp_add<0x141>(z3);
        z4 = dpp_add<0xB1>(z4); z4 = dpp_add<0x4E>(z4); z4 = dpp_add<0x141>(z4);
        z5 = dpp_add<0xB1>(z5); z5 = dpp_add<0x4E>(z5); z5 = dpp_add<0x141>(z5);
        z6 = dpp_add<0xB1>(z6); z6 = dpp_add<0x4E>(z6); z6 = dpp_add<0x141>(z6);
        z7 = dpp_add<0xB1>(z7); z7 = dpp_add<0x4E>(z7); z7 = dpp_add<0x141>(z7);

        const float za = (s & 1) ? z1 : z0;
        const float zb = (s & 1) ? z3 : z2;
        const float zc = (s & 1) ? z5 : z4;
        const float zd = (s & 1) ? z7 : z6;
        const float ze = (s & 2) ? zb : za;
        const float zf = (s & 2) ? zd : zc;
        const float zz = (s & 4) ? zf : ze;
        const float hh = 1.f - 2.f * __builtin_amdgcn_rcpf(__expf(2.f * (zz + bs)) + 1.f);
        hb2[c ^ 1][t] = __float2half(hh);

        if (t < IN) {
            hb2[c ^ 1][HID + t] = __float2half(xv);
            if (tt + 2 < SEQ) xv = xb[(size_t)(tt + 2) * IN + t];
        }
        __syncthreads();
    }

    if (t < OUT) {
        float acc = by[t];
        const float* wy = Wy + (size_t)t * HID;
        #pragma unroll 8
        for (int j = 0; j < HID; ++j)
            acc = fmaf(wy[j], __half2float(hb2[0][j]), acc);
        y[(size_t)b * OUT + t] = acc;
    }
}

extern "C" void kernel_launch(void* const* d_in, const int* in_sizes, int n_in,
                              void* d_out, int out_size, void* d_ws, size_t ws_size,
                              hipStream_t stream) {
    const float* x  = (const float*)d_in[0];
    const float* Wx = (const float*)d_in[1];
    const float* bx = (const float*)d_in[2];
    const float* Wh = (const float*)d_in[3];
    const float* bh = (const float*)d_in[4];
    const float* Wy = (const float*)d_in[5];
    const float* by = (const float*)d_in[6];
    float* y = (float*)d_out;

    const size_t wpk_bytes = (size_t)72 * T * 16;               // 576 KB max
    const size_t xp_bytes  = (size_t)BATCH * SEQ * HID * 2;     // 128 MiB
    if (ws_size >= wpk_bytes + xp_bytes) {
        uint4*  Wpk = (uint4*)d_ws;
        __half* XPh = (__half*)((char*)d_ws + wpk_bytes);
        hipLaunchKernelGGL(prep_w64, dim3(64 * T / 256), dim3(256), 0, stream,
                           Wh, Wpk);
        hipLaunchKernelGGL(prep_xp, dim3(BATCH * SEQ / 16), dim3(256), 0, stream,
                           x, Wx, bx, XPh);
        hipLaunchKernelGGL(rnn_main64, dim3(BATCH), dim3(T), 0, stream,
                           bh, Wy, by, Wpk, XPh, y);
    } else {
        uint4* Wpk = (uint4*)d_ws;
        hipLaunchKernelGGL(prep_w72, dim3(72 * T / 256), dim3(256), 0, stream,
                           Wh, Wx, Wpk);
        hipLaunchKernelGGL(rnn_main72, dim3(BATCH), dim3(T), 0, stream,
                           x, bx, bh, Wy, by, Wpk, y);
    }
}